// Round 1
// baseline (362.494 us; speedup 1.0000x reference)
//
#include <hip/hip_runtime.h>
#include <math.h>

#define NN 16384
#define BB 128
#define FF 32
#define RR 20
#define EE 262144

__device__ __forceinline__ float sspf(float x) {
  // softplus(x) - log(2), numerically stable
  return fmaxf(x, 0.0f) + log1pf(expf(-fabsf(x))) - 0.69314718055994531f;
}

// ---------------- K1: node embeddings hsv[n*32+f] = {hs, hvx, hvy, hvz} ----------------
__global__ __launch_bounds__(256) void k_embed(const float* __restrict__ x,
        const float* __restrict__ ws, const float* __restrict__ wv,
        float4* __restrict__ hsv) {
  int tid = blockIdx.x * 256 + threadIdx.x;   // N*8 threads
  int n = tid >> 3, fq = tid & 7;
  const float* xr = x + (size_t)n * 512;
  float acc[4][4];
#pragma unroll
  for (int k = 0; k < 4; k++)
#pragma unroll
    for (int c = 0; c < 4; c++) acc[k][c] = 0.f;
  for (int bq = 0; bq < 32; bq++) {
    float4 xs4 = *(const float4*)(xr + 4 * bq);
    float4 a0 = *(const float4*)(xr + 128 + 12 * bq);
    float4 a1 = *(const float4*)(xr + 128 + 12 * bq + 4);
    float4 a2 = *(const float4*)(xr + 128 + 12 * bq + 8);
    float xsv[4] = {xs4.x, xs4.y, xs4.z, xs4.w};
    float vv[4][3];
    vv[0][0] = a0.x; vv[0][1] = a0.y; vv[0][2] = a0.z;
    vv[1][0] = a0.w; vv[1][1] = a1.x; vv[1][2] = a1.y;
    vv[2][0] = a1.z; vv[2][1] = a1.w; vv[2][2] = a2.x;
    vv[3][0] = a2.y; vv[3][1] = a2.z; vv[3][2] = a2.w;
#pragma unroll
    for (int bb = 0; bb < 4; bb++) {
      int b = 4 * bq + bb;
      float4 w_s = *(const float4*)(ws + b * 32 + 4 * fq);
      float4 w_v = *(const float4*)(wv + b * 32 + 4 * fq);
      float wsx[4] = {w_s.x, w_s.y, w_s.z, w_s.w};
      float wvx[4] = {w_v.x, w_v.y, w_v.z, w_v.w};
#pragma unroll
      for (int k = 0; k < 4; k++) {
        acc[k][0] += xsv[bb] * wsx[k];
        acc[k][1] += vv[bb][0] * wvx[k];
        acc[k][2] += vv[bb][1] * wvx[k];
        acc[k][3] += vv[bb][2] * wvx[k];
      }
    }
  }
  const float sc = 0.088388347648318447f;  // 1/sqrt(128)
#pragma unroll
  for (int k = 0; k < 4; k++) {
    float4 o;
    o.x = acc[k][0] * sc; o.y = acc[k][1] * sc;
    o.z = acc[k][2] * sc; o.w = acc[k][3] * sc;
    hsv[(size_t)n * 32 + 4 * fq + k] = o;
  }
}

// ---------------- CSR build ----------------
__global__ __launch_bounds__(256) void k_count(const int* __restrict__ idx_i,
        int* __restrict__ cnt, int* __restrict__ pos) {
  int e = blockIdx.x * 256 + threadIdx.x;
  pos[e] = atomicAdd(cnt + idx_i[e], 1);
}

__global__ __launch_bounds__(256) void k_scan(const int* __restrict__ cnt,
        int* __restrict__ offs) {
  __shared__ int part[256];
  int t = threadIdx.x;
  int s = 0;
  for (int i = t * 64; i < t * 64 + 64; ++i) s += cnt[i];
  part[t] = s;
  __syncthreads();
  if (t == 0) {
    int run = 0;
    for (int i = 0; i < 256; i++) { int v = part[i]; part[i] = run; run += v; }
    offs[NN] = run;
  }
  __syncthreads();
  int run = part[t];
  for (int i = t * 64; i < t * 64 + 64; ++i) { offs[i] = run; run += cnt[i]; }
}

__global__ __launch_bounds__(256) void k_fill(const int* __restrict__ idx_i,
        const int* __restrict__ pos, const int* __restrict__ offs,
        int* __restrict__ elist) {
  int e = blockIdx.x * 256 + threadIdx.x;
  elist[offs[idx_i[e]] + pos[e]] = e;
}

// ---------------- KA: per-edge filter MLP first layer: h = ssp(f_ij @ W1 + b1) ----------------
__global__ __launch_bounds__(256) void k_h(const float* __restrict__ fij,
        const float* __restrict__ W1, const float* __restrict__ b1,
        float* __restrict__ hout) {
  __shared__ float sfij[20 * 256];   // [r][edge_local]
  __shared__ float sW1[640];
  __shared__ float sb1[32];
  int t = threadIdx.x;
  int e0 = blockIdx.x * 256;
  for (int i = t; i < 5120; i += 256) {
    float v = fij[(size_t)e0 * 20 + i];
    int el = i / 20, r = i - el * 20;
    sfij[r * 256 + el] = v;
  }
  for (int i = t; i < 640; i += 256) sW1[i] = W1[i];
  if (t < 32) sb1[t] = b1[t];
  __syncthreads();
  int fq = t & 3, el = t >> 2;   // el 0..63 (4 edges each), fq 0..3 (8 fp each)
  int fp0 = fq * 8;
  float acc[4][8];
#pragma unroll
  for (int j = 0; j < 4; j++)
#pragma unroll
    for (int i = 0; i < 8; i++) acc[j][i] = sb1[fp0 + i];
#pragma unroll
  for (int r = 0; r < 20; r++) {
    float4 fe4 = *(const float4*)(sfij + r * 256 + el * 4);
    float fe[4] = {fe4.x, fe4.y, fe4.z, fe4.w};
    float4 wA = *(const float4*)(sW1 + r * 32 + fp0);
    float4 wB = *(const float4*)(sW1 + r * 32 + fp0 + 4);
    float w[8] = {wA.x, wA.y, wA.z, wA.w, wB.x, wB.y, wB.z, wB.w};
#pragma unroll
    for (int j = 0; j < 4; j++)
#pragma unroll
      for (int i = 0; i < 8; i++) acc[j][i] += fe[j] * w[i];
  }
#pragma unroll
  for (int j = 0; j < 4; j++) {
    float4 o1, o2;
    o1.x = sspf(acc[j][0]); o1.y = sspf(acc[j][1]);
    o1.z = sspf(acc[j][2]); o1.w = sspf(acc[j][3]);
    o2.x = sspf(acc[j][4]); o2.y = sspf(acc[j][5]);
    o2.z = sspf(acc[j][6]); o2.w = sspf(acc[j][7]);
    size_t base = ((size_t)(e0 + el * 4 + j)) * 32 + fp0;
    *(float4*)(hout + base) = o1;
    *(float4*)(hout + base + 4) = o2;
  }
}

// ---------------- fused vector output weight: Wv = w1v @ w2v * 1/sqrt(64*128) ----------------
__global__ __launch_bounds__(256) void k_wv(const float* __restrict__ w1v,
        const float* __restrict__ w2v, float* __restrict__ Wv) {
  int o = blockIdx.x * 256 + threadIdx.x;   // 8192
  int m = o >> 7, d = o & 127;
  float s = 0.f;
  for (int b = 0; b < 128; b++) s += w1v[m * 128 + b] * w2v[b * 128 + d];
  Wv[o] = s * 0.011048543456039804f;
}

// ---------------- KB: per-edge W2 GEMV + geometric features + CSR aggregation ----------------
// wave = 1 edge; lane l: f = l>>1, owns W2 columns 6f+kb, 6f+kb+1 (kb = 2*(l&1)) in regs.
__global__ __launch_bounds__(256) void k_edges(
        const float* __restrict__ h, const float* __restrict__ rcut,
        const float* __restrict__ Yr, const int* __restrict__ idxj,
        const float4* __restrict__ hsv,
        const float* __restrict__ W2, const float* __restrict__ b2,
        const int* __restrict__ offs, const int* __restrict__ elist,
        float* __restrict__ node_agg) {
  __shared__ float sW2[6144];
  __shared__ float red[4][64][6];
  int t = threadIdx.x;
  for (int i = t; i < 6144; i += 256) sW2[i] = W2[i];
  __syncthreads();
  int w = t >> 6, l = t & 63;
  int f = l >> 1, kb = (l & 1) * 2;
  float w2r[32][2];
#pragma unroll
  for (int fp = 0; fp < 32; fp++) {
    w2r[fp][0] = sW2[fp * 192 + 6 * f + kb];
    w2r[fp][1] = sW2[fp * 192 + 6 * f + kb + 1];
  }
  float bb0 = b2[6 * f + kb], bb1 = b2[6 * f + kb + 1];
  for (int n = blockIdx.x; n < NN; n += gridDim.x) {
    int start = offs[n], end = offs[n + 1];
    float a0 = 0, a1 = 0, a2 = 0, a3 = 0, a4 = 0, a5 = 0;
    for (int base = start; base < end; base += 4) {
      int ei = base + w;
      if (ei < end) {
        int e = elist[ei];
        int j = idxj[e];
        float rc = rcut[e];
        float ys = Yr[(size_t)e * 4], yx = Yr[(size_t)e * 4 + 1];
        float yy = Yr[(size_t)e * 4 + 2], yz = Yr[(size_t)e * 4 + 3];
        float4 sv = hsv[(size_t)j * 32 + f];
        const float4* hp = (const float4*)(h + (size_t)e * 32);
        float d0 = 0.f, d1 = 0.f;
#pragma unroll
        for (int q = 0; q < 8; q++) {
          float4 h4 = hp[q];
          d0 += h4.x * w2r[4 * q][0] + h4.y * w2r[4 * q + 1][0]
              + h4.z * w2r[4 * q + 2][0] + h4.w * w2r[4 * q + 3][0];
          d1 += h4.x * w2r[4 * q][1] + h4.y * w2r[4 * q + 1][1]
              + h4.z * w2r[4 * q + 2][1] + h4.w * w2r[4 * q + 3][1];
        }
        float wa = (d0 + bb0) * rc, wb = (d1 + bb1) * rc;
        float s = sv.x, vx = sv.y, vy = sv.z, vz = sv.w;
        if (kb == 0) {
          a0 += s * ys * wa;                                          // ch0
          a1 += (vx * yx + vy * yy + vz * yz) * 0.57735026918962576f * wb; // ch1
        } else {
          a0 += s * yx * wa; a1 += s * yy * wa; a2 += s * yz * wa;    // ch2..4
          a3 += vx * ys * wb; a4 += vy * ys * wb; a5 += vz * ys * wb; // ch5..7
        }
      }
    }
    red[w][l][0] = a0; red[w][l][1] = a1; red[w][l][2] = a2;
    red[w][l][3] = a3; red[w][l][4] = a4; red[w][l][5] = a5;
    __syncthreads();
    int f2 = t >> 3, ch = t & 7;
    int sl, slot;
    if (ch < 2) { sl = 2 * f2; slot = ch; }
    else        { sl = 2 * f2 + 1; slot = ch - 2; }
    float sum = red[0][sl][slot] + red[1][sl][slot]
              + red[2][sl][slot] + red[3][sl][slot];
    float* na = node_agg + (size_t)n * 256;
    if (ch == 0)      na[f2] = sum;
    else if (ch == 1) na[32 + f2] = sum;
    else if (ch < 5)  na[64 + f2 * 3 + (ch - 2)] = sum;
    else              na[64 + (32 + f2) * 3 + (ch - 5)] = sum;
    __syncthreads();
  }
}

// ---------------- output transforms: thread owns output column, weights in regs ----------------
__global__ __launch_bounds__(256) void k_os1(const float* __restrict__ node_agg,
        const float* __restrict__ w1s, float* __restrict__ os1) {
  int t = threadIdx.x;
  int d = t & 127, sub = t >> 7;
  int sid = blockIdx.x * 2 + sub;   // 0..1023
  float wr[64];
#pragma unroll
  for (int m = 0; m < 64; m++) wr[m] = w1s[m * 128 + d];
  for (int n = sid; n < NN; n += 1024) {
    const float4* sp = (const float4*)(node_agg + (size_t)n * 256);
    float acc = 0.f;
#pragma unroll
    for (int q = 0; q < 16; q++) {
      float4 s4 = sp[q];
      acc += s4.x * wr[4 * q] + s4.y * wr[4 * q + 1]
           + s4.z * wr[4 * q + 2] + s4.w * wr[4 * q + 3];
    }
    os1[(size_t)n * 128 + d] = sspf(acc * 0.125f);   // 1/sqrt(64)
  }
}

__global__ __launch_bounds__(256) void k_os2(const float* __restrict__ os1,
        const float* __restrict__ w2s, float* __restrict__ out) {
  int t = threadIdx.x;
  int d = t & 127, sub = t >> 7;
  int sid = blockIdx.x * 2 + sub;
  float wr[128];
#pragma unroll
  for (int b = 0; b < 128; b++) wr[b] = w2s[b * 128 + d];
  for (int n = sid; n < NN; n += 1024) {
    const float4* sp = (const float4*)(os1 + (size_t)n * 128);
    float acc = 0.f;
#pragma unroll
    for (int q = 0; q < 32; q++) {
      float4 s4 = sp[q];
      acc += s4.x * wr[4 * q] + s4.y * wr[4 * q + 1]
           + s4.z * wr[4 * q + 2] + s4.w * wr[4 * q + 3];
    }
    out[(size_t)n * 512 + d] = acc * 0.088388347648318447f;   // 1/sqrt(128)
  }
}

__global__ __launch_bounds__(256) void k_ov(const float* __restrict__ node_agg,
        const float* __restrict__ Wv, float* __restrict__ out) {
  int t = threadIdx.x;
  int d = t & 127, sub = t >> 7;
  int sid = blockIdx.x * 2 + sub;
  float wr[64];
#pragma unroll
  for (int m = 0; m < 64; m++) wr[m] = Wv[m * 128 + d];
  for (int n = sid; n < NN; n += 1024) {
    const float4* vp = (const float4*)(node_agg + (size_t)n * 256 + 64);
    float a[3] = {0.f, 0.f, 0.f};
#pragma unroll
    for (int q = 0; q < 48; q++) {
      float4 v4 = vp[q];
      float vals[4] = {v4.x, v4.y, v4.z, v4.w};
#pragma unroll
      for (int jj = 0; jj < 4; jj++) {
        int k = 4 * q + jj;          // compile-time after unroll
        a[k % 3] += vals[jj] * wr[k / 3];
      }
    }
    float* op = out + (size_t)n * 512 + 128 + (size_t)d * 3;
    op[0] = a[0]; op[1] = a[1]; op[2] = a[2];
  }
}

extern "C" void kernel_launch(void* const* d_in, const int* in_sizes, int n_in,
                              void* d_out, int out_size, void* d_ws, size_t ws_size,
                              hipStream_t stream) {
  const float* x    = (const float*)d_in[0];
  const int*   idx_i = (const int*)d_in[1];
  const int*   idx_j = (const int*)d_in[2];
  const float* fij  = (const float*)d_in[3];
  const float* rcut = (const float*)d_in[4];
  const float* Yr   = (const float*)d_in[5];
  const float* w_s  = (const float*)d_in[6];
  const float* w_v  = (const float*)d_in[7];
  const float* W1   = (const float*)d_in[8];
  const float* b1   = (const float*)d_in[9];
  const float* W2   = (const float*)d_in[10];
  const float* b2   = (const float*)d_in[11];
  const float* w1s  = (const float*)d_in[12];
  const float* w1v  = (const float*)d_in[13];
  const float* w2s  = (const float*)d_in[14];
  const float* w2v  = (const float*)d_in[15];
  float* out = (float*)d_out;

  char* ws = (char*)d_ws;
  size_t off = 0;
  auto alloc = [&](size_t bytes) {
    void* p = ws + off;
    off += (bytes + 255) & ~(size_t)255;
    return p;
  };
  float4* hsv  = (float4*)alloc((size_t)NN * 32 * 16);
  float* hbuf  = (float*)alloc((size_t)EE * 32 * 4);
  float* nagg  = (float*)alloc((size_t)NN * 256 * 4);
  float* Wv    = (float*)alloc((size_t)8192 * 4);
  float* os1   = (float*)alloc((size_t)NN * 128 * 4);
  int* cnt     = (int*)alloc((size_t)NN * 4);
  int* offs    = (int*)alloc((size_t)(NN + 1) * 4);
  int* pos     = (int*)alloc((size_t)EE * 4);
  int* elist   = (int*)alloc((size_t)EE * 4);

  hipMemsetAsync(cnt, 0, (size_t)NN * 4, stream);
  k_count<<<EE / 256, 256, 0, stream>>>(idx_i, cnt, pos);
  k_scan<<<1, 256, 0, stream>>>(cnt, offs);
  k_fill<<<EE / 256, 256, 0, stream>>>(idx_i, pos, offs, elist);
  k_embed<<<NN * 8 / 256, 256, 0, stream>>>(x, w_s, w_v, hsv);
  k_h<<<EE / 256, 256, 0, stream>>>(fij, W1, b1, hbuf);
  k_wv<<<32, 256, 0, stream>>>(w1v, w2v, Wv);
  k_edges<<<1024, 256, 0, stream>>>(hbuf, rcut, Yr, idx_j, hsv, W2, b2, offs, elist, nagg);
  k_os1<<<512, 256, 0, stream>>>(nagg, w1s, os1);
  k_os2<<<512, 256, 0, stream>>>(os1, w2s, out);
  k_ov<<<512, 256, 0, stream>>>(nagg, Wv, out);
}